// Round 1
// baseline (1723.354 us; speedup 1.0000x reference)
//
#include <hip/hip_runtime.h>
#include <math.h>

#define NKER 125

// ---------------- scatter: A[dst,kidx,ci] += wprod * x[src,ci]; deg[dst] += 1 ----------------
__global__ __launch_bounds__(256) void scatter_kernel(
    const int* __restrict__ ei, const float* __restrict__ ea,
    const float* __restrict__ x, float* __restrict__ A,
    float* __restrict__ deg, int E, int cinShift) {
  int tid = blockIdx.x * 256 + threadIdx.x;
  int Cin = 1 << cinShift;
  if (tid >= (E << cinShift)) return;
  int e = tid >> cinShift;
  int i = tid & (Cin - 1);
  int src = ei[e];
  int dst = ei[E + e];
  float xv = x[((size_t)src << cinShift) + i];
  float w[3][2];
  int k0[3];
#pragma unroll
  for (int d = 0; d < 3; d++) {
    float p = ea[e * 3 + d] * 4.0f;
    float kf = fminf(fmaxf(floorf(p), 0.0f), 3.0f);
    float f = p - kf;
    k0[d] = (int)kf;
    w[d][0] = 1.0f - f;
    w[d][1] = f;
  }
  int base = dst * NKER;
#pragma unroll
  for (int c = 0; c < 8; c++) {
    int b0 = c & 1, b1 = (c >> 1) & 1, b2 = (c >> 2) & 1;
    float wp = w[0][b0] * w[1][b1] * w[2][b2];
    int kidx = (k0[0] + b0) + 5 * (k0[1] + b1) + 25 * (k0[2] + b2);
    atomicAdd(&A[((size_t)(base + kidx) << cinShift) + i], wp * xv);
  }
  if (i == 0) atomicAdd(&deg[dst], 1.0f);
}

// ---------------- K-split GEMM: acc[m,o] += sum_k A[m,k] * W[k,o] ----------------
template <int COUT>
__global__ __launch_bounds__(256) void gemm_partial(
    const float* __restrict__ A, const float* __restrict__ W,
    float* __restrict__ acc, int M, int Kdim, int ksteps) {
  const int BK = 64;
  const int G = 256 / COUT;       // row groups
  const int RPT = 32 / G;         // rows per thread (BM=32)
  __shared__ float Al[32][BK + 1];
  __shared__ float Wl[BK][COUT];
  int tid = threadIdx.x;
  int o = tid % COUT;
  int g = tid / COUT;
  int mt = blockIdx.x * 32;
  int kstart = blockIdx.y * ksteps * BK;
  int kend = min(Kdim, kstart + ksteps * BK);
  float accr[RPT];
#pragma unroll
  for (int r = 0; r < RPT; r++) accr[r] = 0.0f;
  for (int k0 = kstart; k0 < kend; k0 += BK) {
    for (int t = tid; t < 32 * BK; t += 256) {
      int r = t >> 6, c = t & 63;
      int m = mt + r, k = k0 + c;
      Al[r][c] = (m < M && k < Kdim) ? A[(size_t)m * Kdim + k] : 0.0f;
    }
    for (int t = tid; t < BK * COUT; t += 256) {
      int r = t / COUT, c = t % COUT;
      int k = k0 + r;
      Wl[r][c] = (k < Kdim) ? W[(size_t)k * COUT + c] : 0.0f;
    }
    __syncthreads();
#pragma unroll 8
    for (int kk = 0; kk < BK; kk++) {
      float wv = Wl[kk][o];
#pragma unroll
      for (int r = 0; r < RPT; r++)
        accr[r] = fmaf(Al[g + r * G][kk], wv, accr[r]);
    }
    __syncthreads();
  }
#pragma unroll
  for (int r = 0; r < RPT; r++) {
    int m = mt + g + r * G;
    if (m < M) atomicAdd(&acc[(size_t)m * COUT + o], accr[r]);
  }
}

// ---------------- epilogue: h = elu(acc/max(deg,1) + x@R + b) ----------------
__global__ __launch_bounds__(256) void epilogue_kernel(
    const float* __restrict__ acc, const float* __restrict__ deg,
    const float* __restrict__ x, const float* __restrict__ R,
    const float* __restrict__ b, float* __restrict__ h,
    int N, int Cin, int coutShift) {
  int tid = blockIdx.x * 256 + threadIdx.x;
  int Cout = 1 << coutShift;
  if (tid >= (N << coutShift)) return;
  int n = tid >> coutShift;
  int o = tid & (Cout - 1);
  float s = acc[tid] / fmaxf(deg[n], 1.0f);
  float r = b[o];
  const float* xr = &x[n * Cin];
  for (int i = 0; i < Cin; i++) r = fmaf(xr[i], R[i * Cout + o], r);
  float v = s + r;
  h[tid] = v > 0.0f ? v : expm1f(v);
}

// ---------------- pool: xnext[j,o] += sum_n P[n,j] * h[n,o]  (16 o's per thread) ----------------
__global__ __launch_bounds__(256) void pool_kernel(
    const float* __restrict__ P, const float* __restrict__ h,
    float* __restrict__ xnext, int Nsrc, int Nnext, int coutShift, int chunk) {
  int j = blockIdx.x * 256 + threadIdx.x;
  if (j >= Nnext) return;
  int o0 = blockIdx.z * 16;
  int n0 = blockIdx.y * chunk;
  int n1 = min(Nsrc, n0 + chunk);
  float acc[16];
#pragma unroll
  for (int t = 0; t < 16; t++) acc[t] = 0.0f;
  for (int n = n0; n < n1; n++) {
    float p = P[(size_t)n * Nnext + j];
    const float4* hr = (const float4*)&h[((size_t)n << coutShift) + o0];
    float4 h0 = hr[0], h1 = hr[1], h2 = hr[2], h3 = hr[3];
    acc[0]  = fmaf(p, h0.x, acc[0]);  acc[1]  = fmaf(p, h0.y, acc[1]);
    acc[2]  = fmaf(p, h0.z, acc[2]);  acc[3]  = fmaf(p, h0.w, acc[3]);
    acc[4]  = fmaf(p, h1.x, acc[4]);  acc[5]  = fmaf(p, h1.y, acc[5]);
    acc[6]  = fmaf(p, h1.z, acc[6]);  acc[7]  = fmaf(p, h1.w, acc[7]);
    acc[8]  = fmaf(p, h2.x, acc[8]);  acc[9]  = fmaf(p, h2.y, acc[9]);
    acc[10] = fmaf(p, h2.z, acc[10]); acc[11] = fmaf(p, h2.w, acc[11]);
    acc[12] = fmaf(p, h3.x, acc[12]); acc[13] = fmaf(p, h3.y, acc[13]);
    acc[14] = fmaf(p, h3.z, acc[14]); acc[15] = fmaf(p, h3.w, acc[15]);
  }
#pragma unroll
  for (int t = 0; t < 16; t++)
    atomicAdd(&xnext[((size_t)j << coutShift) + o0 + t], acc[t]);
}

// ---------------- final max over 16 nodes -> out[128] ----------------
__global__ __launch_bounds__(128) void max_kernel(const float* __restrict__ x6,
                                                  float* __restrict__ out) {
  int o = threadIdx.x;
  float m = -3.0e38f;
  for (int n = 0; n < 16; n++) m = fmaxf(m, x6[n * 128 + o]);
  out[o] = m;
}

extern "C" void kernel_launch(void* const* d_in, const int* in_sizes, int n_in,
                              void* d_out, int out_size, void* d_ws, size_t ws_size,
                              hipStream_t stream) {
  static const int NSh[7] = {20000, 5000, 1280, 320, 80, 32, 16};
  static const int ESh[6] = {320000, 80000, 20480, 5120, 1280, 512};
  static const int NFh[7] = {2, 16, 32, 64, 128, 128, 128};
  static const int cinSh[6]  = {1, 4, 5, 6, 7, 7};
  static const int coutSh[6] = {4, 5, 6, 7, 7, 7};
  static const int kstepsTab[6]  = {4, 8, 8, 4, 4, 2};    // BK-steps per block
  static const int kchunksTab[6] = {1, 4, 8, 32, 64, 128}; // grid.y (coverage: steps*chunks*64 >= Kdim)
  static const int poolChunksTab[6] = {16, 16, 8, 8, 4, 2};

  const float* x0 = (const float*)d_in[0];
  const int* ei[6];
  const float* ea[6];
  for (int l = 0; l < 6; l++) {
    ei[l] = (const int*)d_in[1 + 2 * l];
    ea[l] = (const float*)d_in[2 + 2 * l];
  }
  const float* Pm[6];
  for (int l = 0; l < 6; l++) Pm[l] = (const float*)d_in[13 + l];
  const float* Wt[6];
  const float* Rt[6];
  const float* bt[6];
  for (int l = 0; l < 6; l++) {
    Wt[l] = (const float*)d_in[19 + 3 * l];
    Rt[l] = (const float*)d_in[20 + 3 * l];
    bt[l] = (const float*)d_in[21 + 3 * l];
  }

  float* ws = (float*)d_ws;
  float* A    = ws;                 // 10,000,000 floats (max layer: 5000*125*16)
  float* acc  = A + 10000000;       // 320,000
  float* deg  = acc + 320000;       // 20,000
  float* hbuf = deg + 20000;        // 320,000
  float* xA   = hbuf + 320000;      // 80,000
  float* xB   = xA + 80000;         // 80,000

  const float* cur = x0;
  for (int l = 0; l < 6; l++) {
    int N = NSh[l], Nn = NSh[l + 1], Cin = NFh[l], Cout = NFh[l + 1], E = ESh[l];
    int Kdim = NKER * Cin;
    float* xnext = (l & 1) ? xB : xA;

    hipMemsetAsync(A, 0, (size_t)N * NKER * Cin * sizeof(float), stream);
    hipMemsetAsync(deg, 0, (size_t)N * sizeof(float), stream);
    hipMemsetAsync(acc, 0, (size_t)N * Cout * sizeof(float), stream);
    hipMemsetAsync(xnext, 0, (size_t)Nn * Cout * sizeof(float), stream);

    int sthreads = E << cinSh[l];
    scatter_kernel<<<(sthreads + 255) / 256, 256, 0, stream>>>(
        ei[l], ea[l], cur, A, deg, E, cinSh[l]);

    dim3 ggrid((N + 31) / 32, kchunksTab[l]);
    switch (Cout) {
      case 16:
        gemm_partial<16><<<ggrid, 256, 0, stream>>>(A, Wt[l], acc, N, Kdim, kstepsTab[l]);
        break;
      case 32:
        gemm_partial<32><<<ggrid, 256, 0, stream>>>(A, Wt[l], acc, N, Kdim, kstepsTab[l]);
        break;
      case 64:
        gemm_partial<64><<<ggrid, 256, 0, stream>>>(A, Wt[l], acc, N, Kdim, kstepsTab[l]);
        break;
      default:
        gemm_partial<128><<<ggrid, 256, 0, stream>>>(A, Wt[l], acc, N, Kdim, kstepsTab[l]);
        break;
    }

    int ethreads = N << coutSh[l];
    epilogue_kernel<<<(ethreads + 255) / 256, 256, 0, stream>>>(
        acc, deg, cur, Rt[l], bt[l], hbuf, N, Cin, coutSh[l]);

    int chunk = (N + poolChunksTab[l] - 1) / poolChunksTab[l];
    dim3 pgrid((Nn + 255) / 256, poolChunksTab[l], Cout / 16);
    pool_kernel<<<pgrid, 256, 0, stream>>>(Pm[l], hbuf, xnext, N, Nn, coutSh[l], chunk);

    cur = xnext;
  }

  max_kernel<<<1, 128, 0, stream>>>(cur, (float*)d_out);
}

// Round 2
// 1309.357 us; speedup vs baseline: 1.3162x; 1.3162x over previous
//
#include <hip/hip_runtime.h>
#include <math.h>

#define NKER 125

// ---------------- scatter: A[dst,kidx,ci] += wprod * x[src,ci]; deg[dst] += 1 ----------------
__global__ __launch_bounds__(256) void scatter_kernel(
    const int* __restrict__ ei, const float* __restrict__ ea,
    const float* __restrict__ x, float* __restrict__ A,
    float* __restrict__ deg, int E, int cinShift) {
  int tid = blockIdx.x * 256 + threadIdx.x;
  int Cin = 1 << cinShift;
  if (tid >= (E << cinShift)) return;
  int e = tid >> cinShift;
  int i = tid & (Cin - 1);
  int src = ei[e];
  int dst = ei[E + e];
  float xv = x[((size_t)src << cinShift) + i];
  float w[3][2];
  int k0[3];
#pragma unroll
  for (int d = 0; d < 3; d++) {
    float p = ea[e * 3 + d] * 4.0f;
    float kf = fminf(fmaxf(floorf(p), 0.0f), 3.0f);
    float f = p - kf;
    k0[d] = (int)kf;
    w[d][0] = 1.0f - f;
    w[d][1] = f;
  }
  int base = dst * NKER;
#pragma unroll
  for (int c = 0; c < 8; c++) {
    int b0 = c & 1, b1 = (c >> 1) & 1, b2 = (c >> 2) & 1;
    float wp = w[0][b0] * w[1][b1] * w[2][b2];
    int kidx = (k0[0] + b0) + 5 * (k0[1] + b1) + 25 * (k0[2] + b2);
    atomicAdd(&A[((size_t)(base + kidx) << cinShift) + i], wp * xv);
  }
  if (i == 0) atomicAdd(&deg[dst], 1.0f);
}

// ---------------- K-split GEMM: acc[m,o] += sum_k A[m,k] * W[k,o] ----------------
template <int COUT>
__global__ __launch_bounds__(256) void gemm_partial(
    const float* __restrict__ A, const float* __restrict__ W,
    float* __restrict__ acc, int M, int Kdim, int ksteps) {
  const int BK = 64;
  const int G = 256 / COUT;       // row groups
  const int RPT = 32 / G;         // rows per thread (BM=32)
  __shared__ float Al[32][BK + 1];
  __shared__ float Wl[BK][COUT];
  int tid = threadIdx.x;
  int o = tid % COUT;
  int g = tid / COUT;
  int mt = blockIdx.x * 32;
  int kstart = blockIdx.y * ksteps * BK;
  int kend = min(Kdim, kstart + ksteps * BK);
  float accr[RPT];
#pragma unroll
  for (int r = 0; r < RPT; r++) accr[r] = 0.0f;
  for (int k0 = kstart; k0 < kend; k0 += BK) {
    for (int t = tid; t < 32 * BK; t += 256) {
      int r = t >> 6, c = t & 63;
      int m = mt + r, k = k0 + c;
      Al[r][c] = (m < M && k < Kdim) ? A[(size_t)m * Kdim + k] : 0.0f;
    }
    for (int t = tid; t < BK * COUT; t += 256) {
      int r = t / COUT, c = t % COUT;
      int k = k0 + r;
      Wl[r][c] = (k < Kdim) ? W[(size_t)k * COUT + c] : 0.0f;
    }
    __syncthreads();
#pragma unroll 8
    for (int kk = 0; kk < BK; kk++) {
      float wv = Wl[kk][o];
#pragma unroll
      for (int r = 0; r < RPT; r++)
        accr[r] = fmaf(Al[g + r * G][kk], wv, accr[r]);
    }
    __syncthreads();
  }
#pragma unroll
  for (int r = 0; r < RPT; r++) {
    int m = mt + g + r * G;
    if (m < M) atomicAdd(&acc[(size_t)m * COUT + o], accr[r]);
  }
}

// ---------------- epilogue: h = elu(acc/max(deg,1) + x@R + b) ----------------
__global__ __launch_bounds__(256) void epilogue_kernel(
    const float* __restrict__ acc, const float* __restrict__ deg,
    const float* __restrict__ x, const float* __restrict__ R,
    const float* __restrict__ b, float* __restrict__ h,
    int N, int Cin, int coutShift) {
  int tid = blockIdx.x * 256 + threadIdx.x;
  int Cout = 1 << coutShift;
  if (tid >= (N << coutShift)) return;
  int n = tid >> coutShift;
  int o = tid & (Cout - 1);
  float s = acc[tid] / fmaxf(deg[n], 1.0f);
  float r = b[o];
  const float* xr = &x[n * Cin];
  for (int i = 0; i < Cin; i++) r = fmaf(xr[i], R[i * Cout + o], r);
  float v = s + r;
  h[tid] = v > 0.0f ? v : expm1f(v);
}

// ---------------- pool v2: partial[c][j][o] = sum_{n in chunk c} P[n,j] * h[n,o] ----------------
// Each thread: 4 consecutive j (one float4 of P per n) x 8 consecutive o = 32 accumulators.
// Unroll n by 4 -> 4 independent 16B P loads in flight per lane.
__global__ __launch_bounds__(256) void pool2_kernel(
    const float* __restrict__ P, const float* __restrict__ h,
    float* __restrict__ partial, int Nsrc, int Nnext, int coutShift,
    int chunk, int items) {
  int item = blockIdx.x * 256 + threadIdx.x;
  if (item >= items) return;
  int nj4 = Nnext >> 2;
  int j4 = item % nj4;
  int og = item / nj4;
  int j0 = j4 << 2;
  int o0 = og << 3;
  int Cout = 1 << coutShift;
  int c = blockIdx.y;
  int n0 = c * chunk;
  int n1 = min(Nsrc, n0 + chunk);
  float acc[4][8];
#pragma unroll
  for (int a = 0; a < 4; a++)
#pragma unroll
    for (int b = 0; b < 8; b++) acc[a][b] = 0.0f;
  int n = n0;
  for (; n + 4 <= n1; n += 4) {
    float4 p[4], hA[4], hB[4];
#pragma unroll
    for (int u = 0; u < 4; u++) {
      p[u] = *(const float4*)&P[(size_t)(n + u) * Nnext + j0];
      const float* hr = &h[((size_t)(n + u) << coutShift) + o0];
      hA[u] = *(const float4*)hr;
      hB[u] = *(const float4*)(hr + 4);
    }
#pragma unroll
    for (int u = 0; u < 4; u++) {
      float pj[4] = {p[u].x, p[u].y, p[u].z, p[u].w};
      float ho[8] = {hA[u].x, hA[u].y, hA[u].z, hA[u].w,
                     hB[u].x, hB[u].y, hB[u].z, hB[u].w};
#pragma unroll
      for (int a = 0; a < 4; a++)
#pragma unroll
        for (int b = 0; b < 8; b++) acc[a][b] = fmaf(pj[a], ho[b], acc[a][b]);
    }
  }
  for (; n < n1; n++) {
    float4 pv = *(const float4*)&P[(size_t)n * Nnext + j0];
    const float* hr = &h[((size_t)n << coutShift) + o0];
    float4 hA0 = *(const float4*)hr;
    float4 hB0 = *(const float4*)(hr + 4);
    float pj[4] = {pv.x, pv.y, pv.z, pv.w};
    float ho[8] = {hA0.x, hA0.y, hA0.z, hA0.w, hB0.x, hB0.y, hB0.z, hB0.w};
#pragma unroll
    for (int a = 0; a < 4; a++)
#pragma unroll
      for (int b = 0; b < 8; b++) acc[a][b] = fmaf(pj[a], ho[b], acc[a][b]);
  }
  float* pp = partial + ((size_t)c * Nnext + j0) * Cout + o0;
#pragma unroll
  for (int a = 0; a < 4; a++) {
    *(float4*)(pp + (size_t)a * Cout) =
        make_float4(acc[a][0], acc[a][1], acc[a][2], acc[a][3]);
    *(float4*)(pp + (size_t)a * Cout + 4) =
        make_float4(acc[a][4], acc[a][5], acc[a][6], acc[a][7]);
  }
}

// ---------------- pool reduce: xnext[i4] = sum_c partial[c][i4] ----------------
__global__ __launch_bounds__(256) void pool_reduce_kernel(
    const float4* __restrict__ partial, float4* __restrict__ xnext,
    int NC4, int nchunks) {
  int i = blockIdx.x * 256 + threadIdx.x;
  if (i >= NC4) return;
  float4 s = make_float4(0.0f, 0.0f, 0.0f, 0.0f);
  for (int c = 0; c < nchunks; c++) {
    float4 v = partial[(size_t)c * NC4 + i];
    s.x += v.x; s.y += v.y; s.z += v.z; s.w += v.w;
  }
  xnext[i] = s;
}

// ---------------- final max over 16 nodes -> out[128] ----------------
__global__ __launch_bounds__(128) void max_kernel(const float* __restrict__ x6,
                                                  float* __restrict__ out) {
  int o = threadIdx.x;
  float m = -3.0e38f;
  for (int n = 0; n < 16; n++) m = fmaxf(m, x6[n * 128 + o]);
  out[o] = m;
}

extern "C" void kernel_launch(void* const* d_in, const int* in_sizes, int n_in,
                              void* d_out, int out_size, void* d_ws, size_t ws_size,
                              hipStream_t stream) {
  static const int NSh[7] = {20000, 5000, 1280, 320, 80, 32, 16};
  static const int ESh[6] = {320000, 80000, 20480, 5120, 1280, 512};
  static const int NFh[7] = {2, 16, 32, 64, 128, 128, 128};
  static const int cinSh[6]  = {1, 4, 5, 6, 7, 7};
  static const int coutSh[6] = {4, 5, 6, 7, 7, 7};
  static const int kstepsTab[6]  = {4, 8, 8, 4, 4, 2};    // BK-steps per block
  static const int kchunksTab[6] = {1, 4, 8, 32, 64, 128}; // grid.y (coverage: steps*chunks*64 >= Kdim)
  static const int poolChunksTab[6] = {64, 32, 32, 16, 8, 4};

  const float* x0 = (const float*)d_in[0];
  const int* ei[6];
  const float* ea[6];
  for (int l = 0; l < 6; l++) {
    ei[l] = (const int*)d_in[1 + 2 * l];
    ea[l] = (const float*)d_in[2 + 2 * l];
  }
  const float* Pm[6];
  for (int l = 0; l < 6; l++) Pm[l] = (const float*)d_in[13 + l];
  const float* Wt[6];
  const float* Rt[6];
  const float* bt[6];
  for (int l = 0; l < 6; l++) {
    Wt[l] = (const float*)d_in[19 + 3 * l];
    Rt[l] = (const float*)d_in[20 + 3 * l];
    bt[l] = (const float*)d_in[21 + 3 * l];
  }

  float* ws = (float*)d_ws;
  float* A    = ws;                 // 10,000,000 floats; reused as pool partials (max 64*80000 = 5.12M)
  float* acc  = A + 10000000;       // 320,000
  float* deg  = acc + 320000;       // 20,000
  float* hbuf = deg + 20000;        // 320,000
  float* xA   = hbuf + 320000;      // 80,000
  float* xB   = xA + 80000;         // 80,000

  const float* cur = x0;
  for (int l = 0; l < 6; l++) {
    int N = NSh[l], Nn = NSh[l + 1], Cin = NFh[l], Cout = NFh[l + 1], E = ESh[l];
    int Kdim = NKER * Cin;
    float* xnext = (l & 1) ? xB : xA;

    hipMemsetAsync(A, 0, (size_t)N * NKER * Cin * sizeof(float), stream);
    hipMemsetAsync(deg, 0, (size_t)N * sizeof(float), stream);
    hipMemsetAsync(acc, 0, (size_t)N * Cout * sizeof(float), stream);

    int sthreads = E << cinSh[l];
    scatter_kernel<<<(sthreads + 255) / 256, 256, 0, stream>>>(
        ei[l], ea[l], cur, A, deg, E, cinSh[l]);

    dim3 ggrid((N + 31) / 32, kchunksTab[l]);
    switch (Cout) {
      case 16:
        gemm_partial<16><<<ggrid, 256, 0, stream>>>(A, Wt[l], acc, N, Kdim, kstepsTab[l]);
        break;
      case 32:
        gemm_partial<32><<<ggrid, 256, 0, stream>>>(A, Wt[l], acc, N, Kdim, kstepsTab[l]);
        break;
      case 64:
        gemm_partial<64><<<ggrid, 256, 0, stream>>>(A, Wt[l], acc, N, Kdim, kstepsTab[l]);
        break;
      default:
        gemm_partial<128><<<ggrid, 256, 0, stream>>>(A, Wt[l], acc, N, Kdim, kstepsTab[l]);
        break;
    }

    int ethreads = N << coutSh[l];
    epilogue_kernel<<<(ethreads + 255) / 256, 256, 0, stream>>>(
        acc, deg, cur, Rt[l], bt[l], hbuf, N, Cin, coutSh[l]);

    // pool: partial sums into A region (A is dead after gemm), then reduce
    int pc = poolChunksTab[l];
    int chunk = (N + pc - 1) / pc;
    int items = (Nn >> 2) * (Cout >> 3);
    dim3 pgrid((items + 255) / 256, pc);
    pool2_kernel<<<pgrid, 256, 0, stream>>>(Pm[l], hbuf, A, N, Nn, coutSh[l], chunk, items);
    int NC4 = (Nn * Cout) >> 2;
    pool_reduce_kernel<<<(NC4 + 255) / 256, 256, 0, stream>>>(
        (const float4*)A, (float4*)xnext, NC4, pc);

    cur = xnext;
  }

  max_kernel<<<1, 128, 0, stream>>>(cur, (float*)d_out);
}

// Round 3
// 941.068 us; speedup vs baseline: 1.8313x; 1.3914x over previous
//
#include <hip/hip_runtime.h>
#include <math.h>

#define NKER 125

// ---------------- scatter: A[dst,kidx,ci] += wprod * x[src,ci]; deg[dst] += 1 ----------------
__global__ __launch_bounds__(256) void scatter_kernel(
    const int* __restrict__ ei, const float* __restrict__ ea,
    const float* __restrict__ x, float* __restrict__ A,
    float* __restrict__ deg, int E, int cinShift) {
  int tid = blockIdx.x * 256 + threadIdx.x;
  int Cin = 1 << cinShift;
  if (tid >= (E << cinShift)) return;
  int e = tid >> cinShift;
  int i = tid & (Cin - 1);
  int src = ei[e];
  int dst = ei[E + e];
  float xv = x[((size_t)src << cinShift) + i];
  float w[3][2];
  int k0[3];
#pragma unroll
  for (int d = 0; d < 3; d++) {
    float p = ea[e * 3 + d] * 4.0f;
    float kf = fminf(fmaxf(floorf(p), 0.0f), 3.0f);
    float f = p - kf;
    k0[d] = (int)kf;
    w[d][0] = 1.0f - f;
    w[d][1] = f;
  }
  int base = dst * NKER;
#pragma unroll
  for (int c = 0; c < 8; c++) {
    int b0 = c & 1, b1 = (c >> 1) & 1, b2 = (c >> 2) & 1;
    float wp = w[0][b0] * w[1][b1] * w[2][b2];
    int kidx = (k0[0] + b0) + 5 * (k0[1] + b1) + 25 * (k0[2] + b2);
    atomicAdd(&A[((size_t)(base + kidx) << cinShift) + i], wp * xv);
  }
  if (i == 0) atomicAdd(&deg[dst], 1.0f);
}

// ---------------- GEMM v2: register-tiled 4x4, transposed-A LDS, k-chunk atomics ----------------
template <int BM, int COUT, int NT>
__global__ __launch_bounds__(NT) void gemm2_kernel(
    const float* __restrict__ A, const float* __restrict__ W,
    float* __restrict__ acc, int M, int Kdim, int ktiles) {
  const int BK = 32;
  __shared__ float At[BK][BM + 4];
  __shared__ float Wl[BK][COUT];
  const int TC = COUT / 4;
  int tid = threadIdx.x;
  int tc = tid % TC;
  int tr = tid / TC;
  int m0 = blockIdx.x * BM;
  int kbeg = blockIdx.y * ktiles * BK;
  int kend = min(Kdim, kbeg + ktiles * BK);
  float ar[4][4];
#pragma unroll
  for (int i = 0; i < 4; i++)
#pragma unroll
    for (int j = 0; j < 4; j++) ar[i][j] = 0.0f;

  for (int k0 = kbeg; k0 < kend; k0 += BK) {
    bool fullk = (k0 + BK <= Kdim) && ((Kdim & 3) == 0);
    if (fullk) {
      for (int t = tid; t < BM * (BK / 4); t += NT) {
        int c4 = t % (BK / 4), r = t / (BK / 4);
        int m = m0 + r;
        float4 v = make_float4(0.0f, 0.0f, 0.0f, 0.0f);
        if (m < M) v = *(const float4*)&A[(size_t)m * Kdim + k0 + c4 * 4];
        At[c4 * 4 + 0][r] = v.x; At[c4 * 4 + 1][r] = v.y;
        At[c4 * 4 + 2][r] = v.z; At[c4 * 4 + 3][r] = v.w;
      }
      for (int t = tid; t < BK * COUT / 4; t += NT)
        ((float4*)&Wl[0][0])[t] = ((const float4*)&W[(size_t)k0 * COUT])[t];
    } else {
      for (int t = tid; t < BM * (BK / 4); t += NT) {
        int c4 = t % (BK / 4), r = t / (BK / 4);
        int m = m0 + r;
#pragma unroll
        for (int u = 0; u < 4; u++) {
          int k = k0 + c4 * 4 + u;
          At[c4 * 4 + u][r] = (m < M && k < Kdim) ? A[(size_t)m * Kdim + k] : 0.0f;
        }
      }
      for (int t = tid; t < BK * COUT; t += NT) {
        int kk = t / COUT, o = t % COUT;
        int k = k0 + kk;
        Wl[kk][o] = (k < Kdim) ? W[(size_t)k * COUT + o] : 0.0f;
      }
    }
    __syncthreads();
#pragma unroll
    for (int kk = 0; kk < BK; kk++) {
      float4 a = *(const float4*)&At[kk][tr * 4];
      float4 w = *(const float4*)&Wl[kk][tc * 4];
      float av[4] = {a.x, a.y, a.z, a.w};
      float wv[4] = {w.x, w.y, w.z, w.w};
#pragma unroll
      for (int i = 0; i < 4; i++)
#pragma unroll
        for (int j = 0; j < 4; j++)
          ar[i][j] = fmaf(av[i], wv[j], ar[i][j]);
    }
    __syncthreads();
  }
#pragma unroll
  for (int i = 0; i < 4; i++) {
    int m = m0 + tr * 4 + i;
    if (m < M) {
#pragma unroll
      for (int j = 0; j < 4; j++)
        atomicAdd(&acc[(size_t)m * COUT + tc * 4 + j], ar[i][j]);
    }
  }
}

// ---------------- epilogue: h = elu(acc/max(deg,1) + x@R + b) ----------------
__global__ __launch_bounds__(256) void epilogue_kernel(
    const float* __restrict__ acc, const float* __restrict__ deg,
    const float* __restrict__ x, const float* __restrict__ R,
    const float* __restrict__ b, float* __restrict__ h,
    int N, int Cin, int coutShift) {
  int tid = blockIdx.x * 256 + threadIdx.x;
  int Cout = 1 << coutShift;
  if (tid >= (N << coutShift)) return;
  int n = tid >> coutShift;
  int o = tid & (Cout - 1);
  float s = acc[tid] / fmaxf(deg[n], 1.0f);
  float r = b[o];
  const float* xr = &x[n * Cin];
  for (int i = 0; i < Cin; i++) r = fmaf(xr[i], R[i * Cout + o], r);
  float v = s + r;
  h[tid] = v > 0.0f ? v : expm1f(v);
}

// ---------------- pool v3: h tile staged in LDS; partial[c][j][o] ----------------
template <int COUT>
__global__ __launch_bounds__(256) void pool3_kernel(
    const float* __restrict__ P, const float* __restrict__ h,
    float* __restrict__ partial, int Nsrc, int Nnext, int chunk, int items) {
  extern __shared__ float hs[];
  int c = blockIdx.y;
  int n0 = c * chunk;
  int n1 = min(Nsrc, n0 + chunk);
  int len = n1 - n0;
  for (int t = threadIdx.x; t < len * (COUT / 4); t += 256)
    ((float4*)hs)[t] = ((const float4*)&h[(size_t)n0 * COUT])[t];
  __syncthreads();
  int item = blockIdx.x * 256 + threadIdx.x;
  if (item >= items) return;
  int nj4 = Nnext >> 2;
  int j0 = (item % nj4) << 2;
  int o0 = (item / nj4) << 3;
  float ac[4][8];
#pragma unroll
  for (int a = 0; a < 4; a++)
#pragma unroll
    for (int b = 0; b < 8; b++) ac[a][b] = 0.0f;
  const float* Pb = P + j0;
  int n = 0;
  for (; n + 4 <= len; n += 4) {
    float4 p0 = *(const float4*)&Pb[(size_t)(n0 + n + 0) * Nnext];
    float4 p1 = *(const float4*)&Pb[(size_t)(n0 + n + 1) * Nnext];
    float4 p2 = *(const float4*)&Pb[(size_t)(n0 + n + 2) * Nnext];
    float4 p3 = *(const float4*)&Pb[(size_t)(n0 + n + 3) * Nnext];
#pragma unroll
    for (int u = 0; u < 4; u++) {
      const float* hr = &hs[(n + u) * COUT + o0];
      float4 hA = *(const float4*)hr;
      float4 hB = *(const float4*)(hr + 4);
      float4 p = (u == 0) ? p0 : (u == 1) ? p1 : (u == 2) ? p2 : p3;
      float pj[4] = {p.x, p.y, p.z, p.w};
      float ho[8] = {hA.x, hA.y, hA.z, hA.w, hB.x, hB.y, hB.z, hB.w};
#pragma unroll
      for (int a = 0; a < 4; a++)
#pragma unroll
        for (int b = 0; b < 8; b++) ac[a][b] = fmaf(pj[a], ho[b], ac[a][b]);
    }
  }
  for (; n < len; n++) {
    float4 p = *(const float4*)&Pb[(size_t)(n0 + n) * Nnext];
    const float* hr = &hs[n * COUT + o0];
    float4 hA = *(const float4*)hr;
    float4 hB = *(const float4*)(hr + 4);
    float pj[4] = {p.x, p.y, p.z, p.w};
    float ho[8] = {hA.x, hA.y, hA.z, hA.w, hB.x, hB.y, hB.z, hB.w};
#pragma unroll
    for (int a = 0; a < 4; a++)
#pragma unroll
      for (int b = 0; b < 8; b++) ac[a][b] = fmaf(pj[a], ho[b], ac[a][b]);
  }
  float* pp = partial + ((size_t)c * Nnext + j0) * COUT + o0;
#pragma unroll
  for (int a = 0; a < 4; a++) {
    *(float4*)(pp + (size_t)a * COUT) =
        make_float4(ac[a][0], ac[a][1], ac[a][2], ac[a][3]);
    *(float4*)(pp + (size_t)a * COUT + 4) =
        make_float4(ac[a][4], ac[a][5], ac[a][6], ac[a][7]);
  }
}

// ---------------- pool reduce: xnext[i4] (+)= sum_{c in group} partial[c][i4] ----------------
__global__ __launch_bounds__(256) void pool_reduce_kernel(
    const float4* __restrict__ partial, float* __restrict__ xnext,
    int NC4, int chunks, int cg) {
  int i = blockIdx.x * 256 + threadIdx.x;
  if (i >= NC4) return;
  int c0 = blockIdx.y * cg;
  int c1 = min(chunks, c0 + cg);
  float4 s = make_float4(0.0f, 0.0f, 0.0f, 0.0f);
  for (int c = c0; c < c1; c++) {
    float4 v = partial[(size_t)c * NC4 + i];
    s.x += v.x; s.y += v.y; s.z += v.z; s.w += v.w;
  }
  if (gridDim.y == 1) {
    ((float4*)xnext)[i] = s;
  } else {
    atomicAdd(&xnext[4 * i + 0], s.x);
    atomicAdd(&xnext[4 * i + 1], s.y);
    atomicAdd(&xnext[4 * i + 2], s.z);
    atomicAdd(&xnext[4 * i + 3], s.w);
  }
}

// ---------------- final max over 16 nodes -> out[128] ----------------
__global__ __launch_bounds__(128) void max_kernel(const float* __restrict__ x6,
                                                  float* __restrict__ out) {
  int o = threadIdx.x;
  float m = -3.0e38f;
  for (int n = 0; n < 16; n++) m = fmaxf(m, x6[n * 128 + o]);
  out[o] = m;
}

extern "C" void kernel_launch(void* const* d_in, const int* in_sizes, int n_in,
                              void* d_out, int out_size, void* d_ws, size_t ws_size,
                              hipStream_t stream) {
  static const int NSh[7] = {20000, 5000, 1280, 320, 80, 32, 16};
  static const int ESh[6] = {320000, 80000, 20480, 5120, 1280, 512};
  static const int NFh[7] = {2, 16, 32, 64, 128, 128, 128};
  static const int cinSh[6]  = {1, 4, 5, 6, 7, 7};
  static const int coutSh[6] = {4, 5, 6, 7, 7, 7};
  static const int kchunksTab[6] = {4, 8, 16, 32, 64, 128};
  static const int ktilesTab[6]  = {2, 8, 8, 8, 8, 4};
  static const int poolChunksTab[6] = {120, 64, 16, 8, 4, 2};
  static const int poolGroupsTab[6] = {8, 4, 1, 1, 1, 1};

  const float* x0 = (const float*)d_in[0];
  const int* ei[6];
  const float* ea[6];
  for (int l = 0; l < 6; l++) {
    ei[l] = (const int*)d_in[1 + 2 * l];
    ea[l] = (const float*)d_in[2 + 2 * l];
  }
  const float* Pm[6];
  for (int l = 0; l < 6; l++) Pm[l] = (const float*)d_in[13 + l];
  const float* Wt[6];
  const float* Rt[6];
  const float* bt[6];
  for (int l = 0; l < 6; l++) {
    Wt[l] = (const float*)d_in[19 + 3 * l];
    Rt[l] = (const float*)d_in[20 + 3 * l];
    bt[l] = (const float*)d_in[21 + 3 * l];
  }

  float* ws = (float*)d_ws;
  const size_t AREG = 10165000;     // fits max(Aused + N*Cout + N) (layer1) and pool partials
  float* A    = ws;
  float* hbuf = ws + AREG;          // 320,000
  float* xA   = hbuf + 320000;      // 80,000
  float* xB   = xA + 80000;         // 80,000

  const float* cur = x0;
  for (int l = 0; l < 6; l++) {
    int N = NSh[l], Nn = NSh[l + 1], Cin = NFh[l], Cout = NFh[l + 1], E = ESh[l];
    int Kdim = NKER * Cin;
    float* xnext = (l & 1) ? xB : xA;
    size_t Aused = (size_t)N * NKER * Cin;
    float* accL = A + Aused;
    float* degL = accL + (size_t)N * Cout;

    // one fused memset: A-used + acc + deg; plus xnext (reduce may atomically accumulate)
    hipMemsetAsync(A, 0, (Aused + (size_t)N * Cout + N) * sizeof(float), stream);
    hipMemsetAsync(xnext, 0, (size_t)Nn * Cout * sizeof(float), stream);

    int sthreads = E << cinSh[l];
    scatter_kernel<<<(sthreads + 255) / 256, 256, 0, stream>>>(
        ei[l], ea[l], cur, A, degL, E, cinSh[l]);

    // GEMM
    {
      int kchunks = kchunksTab[l], ktiles = ktilesTab[l];
      switch (l) {
        case 0: {
          dim3 g((N + 127) / 128, kchunks);
          gemm2_kernel<128, 16, 128><<<g, 128, 0, stream>>>(A, Wt[l], accL, N, Kdim, ktiles);
          break;
        }
        case 1: {
          dim3 g((N + 127) / 128, kchunks);
          gemm2_kernel<128, 32, 256><<<g, 256, 0, stream>>>(A, Wt[l], accL, N, Kdim, ktiles);
          break;
        }
        case 2: {
          dim3 g((N + 63) / 64, kchunks);
          gemm2_kernel<64, 64, 256><<<g, 256, 0, stream>>>(A, Wt[l], accL, N, Kdim, ktiles);
          break;
        }
        default: {
          dim3 g((N + 31) / 32, kchunks);
          gemm2_kernel<32, 128, 256><<<g, 256, 0, stream>>>(A, Wt[l], accL, N, Kdim, ktiles);
          break;
        }
      }
    }

    int ethreads = N << coutSh[l];
    epilogue_kernel<<<(ethreads + 255) / 256, 256, 0, stream>>>(
        accL, degL, cur, Rt[l], bt[l], hbuf, N, Cin, coutSh[l]);

    // pool: partials into A region (dead after epilogue), then grouped reduce
    int pc = poolChunksTab[l];
    int chunk = (N + pc - 1) / pc;
    int items = (Nn >> 2) * (Cout >> 3);
    size_t ldsB = (size_t)chunk * Cout * sizeof(float);
    dim3 pgrid((items + 255) / 256, pc);
    switch (Cout) {
      case 16:
        pool3_kernel<16><<<pgrid, 256, ldsB, stream>>>(Pm[l], hbuf, A, N, Nn, chunk, items);
        break;
      case 32:
        pool3_kernel<32><<<pgrid, 256, ldsB, stream>>>(Pm[l], hbuf, A, N, Nn, chunk, items);
        break;
      case 64:
        pool3_kernel<64><<<pgrid, 256, ldsB, stream>>>(Pm[l], hbuf, A, N, Nn, chunk, items);
        break;
      default:
        pool3_kernel<128><<<pgrid, 256, ldsB, stream>>>(Pm[l], hbuf, A, N, Nn, chunk, items);
        break;
    }
    int NC4 = (Nn * Cout) >> 2;
    int groups = poolGroupsTab[l];
    int cg = (pc + groups - 1) / groups;
    dim3 rgrid((NC4 + 255) / 256, groups);
    pool_reduce_kernel<<<rgrid, 256, 0, stream>>>(
        (const float4*)A, xnext, NC4, pc, cg);

    cur = xnext;
  }

  max_kernel<<<1, 128, 0, stream>>>(cur, (float*)d_out);
}

// Round 4
// 879.594 us; speedup vs baseline: 1.9593x; 1.0699x over previous
//
#include <hip/hip_runtime.h>
#include <math.h>

#define NKER 125

// ---------------- scatter: A[dst*KS + kidx*Cin + i] += wprod * x[src,ci]; deg[dst] += 1 ----------------
__global__ __launch_bounds__(256) void scatter_kernel(
    const int* __restrict__ ei, const float* __restrict__ ea,
    const float* __restrict__ x, float* __restrict__ A,
    float* __restrict__ deg, int E, int cinShift, int KS) {
  int tid = blockIdx.x * 256 + threadIdx.x;
  int Cin = 1 << cinShift;
  if (tid >= (E << cinShift)) return;
  int e = tid >> cinShift;
  int i = tid & (Cin - 1);
  int src = ei[e];
  int dst = ei[E + e];
  float xv = x[((size_t)src << cinShift) + i];
  float w[3][2];
  int k0[3];
#pragma unroll
  for (int d = 0; d < 3; d++) {
    float p = ea[e * 3 + d] * 4.0f;
    float kf = fminf(fmaxf(floorf(p), 0.0f), 3.0f);
    float f = p - kf;
    k0[d] = (int)kf;
    w[d][0] = 1.0f - f;
    w[d][1] = f;
  }
  float* Arow = A + (size_t)dst * KS + i;
#pragma unroll
  for (int c = 0; c < 8; c++) {
    int b0 = c & 1, b1 = (c >> 1) & 1, b2 = (c >> 2) & 1;
    float wp = w[0][b0] * w[1][b1] * w[2][b2];
    int kidx = (k0[0] + b0) + 5 * (k0[1] + b1) + 25 * (k0[2] + b2);
    atomicAdd(&Arow[kidx << cinShift], wp * xv);
  }
  if (i == 0) atomicAdd(&deg[dst], 1.0f);
}

// ---------------- GEMM v3: register-tiled 4x4, float4 staging, partials out (no atomics) ----------------
template <int BM, int COUT, int NT>
__global__ __launch_bounds__(NT) void gemm3_kernel(
    const float* __restrict__ A, const float* __restrict__ W,
    float* __restrict__ gpart, int M, int Kdim, int KS, int ktiles) {
  const int BK = 32;
  __shared__ float At[BK][BM + 4];
  __shared__ float Wl[BK][COUT];
  const int TC = COUT / 4;
  int tid = threadIdx.x;
  int tc = tid % TC;
  int tr = tid / TC;
  int m0 = blockIdx.x * BM;
  int kbeg = blockIdx.y * ktiles * BK;
  int kend = min(KS, kbeg + ktiles * BK);
  float ar[4][4];
#pragma unroll
  for (int i = 0; i < 4; i++)
#pragma unroll
    for (int j = 0; j < 4; j++) ar[i][j] = 0.0f;

  for (int k0 = kbeg; k0 < kend; k0 += BK) {
    // A tile: always float4 (KS padded to %32, pad region is zero)
    for (int t = tid; t < BM * (BK / 4); t += NT) {
      int c4 = t % (BK / 4), r = t / (BK / 4);
      int m = m0 + r;
      float4 v = make_float4(0.0f, 0.0f, 0.0f, 0.0f);
      if (m < M) v = *(const float4*)&A[(size_t)m * KS + k0 + c4 * 4];
      At[c4 * 4 + 0][r] = v.x; At[c4 * 4 + 1][r] = v.y;
      At[c4 * 4 + 2][r] = v.z; At[c4 * 4 + 3][r] = v.w;
    }
    // W tile: vector when fully in-range, else bounds-checked
    int kleft = Kdim - k0;
    if (kleft >= BK) {
      for (int t = tid; t < BK * COUT / 4; t += NT)
        ((float4*)&Wl[0][0])[t] = ((const float4*)&W[(size_t)k0 * COUT])[t];
    } else {
      for (int t = tid; t < BK * COUT; t += NT) {
        int kk = t / COUT, o = t % COUT;
        Wl[kk][o] = (kk < kleft) ? W[(size_t)(k0 + kk) * COUT + o] : 0.0f;
      }
    }
    __syncthreads();
#pragma unroll
    for (int kk = 0; kk < BK; kk++) {
      float4 a = *(const float4*)&At[kk][tr * 4];
      float4 w = *(const float4*)&Wl[kk][tc * 4];
      float av[4] = {a.x, a.y, a.z, a.w};
      float wv[4] = {w.x, w.y, w.z, w.w};
#pragma unroll
      for (int i = 0; i < 4; i++)
#pragma unroll
        for (int j = 0; j < 4; j++)
          ar[i][j] = fmaf(av[i], wv[j], ar[i][j]);
    }
    __syncthreads();
  }
  float* gp = gpart + ((size_t)blockIdx.y * M) * COUT + tc * 4;
#pragma unroll
  for (int i = 0; i < 4; i++) {
    int m = m0 + tr * 4 + i;
    if (m < M)
      *(float4*)(gp + (size_t)m * COUT) =
          make_float4(ar[i][0], ar[i][1], ar[i][2], ar[i][3]);
  }
}

// ---------------- epilogue: h = elu(sum_c gpart[c]/max(deg,1) + x@R + b) ----------------
__global__ __launch_bounds__(256) void epilogue_kernel(
    const float* __restrict__ gpart, const float* __restrict__ deg,
    const float* __restrict__ x, const float* __restrict__ R,
    const float* __restrict__ b, float* __restrict__ h,
    int N, int Cin, int coutShift, int kchunks) {
  int tid = blockIdx.x * 256 + threadIdx.x;
  int Cout = 1 << coutShift;
  if (tid >= (N << coutShift)) return;
  int n = tid >> coutShift;
  int o = tid & (Cout - 1);
  size_t stride = (size_t)N << coutShift;
  float s = 0.0f;
  for (int c = 0; c < kchunks; c++) s += gpart[(size_t)c * stride + tid];
  s /= fmaxf(deg[n], 1.0f);
  float r = b[o];
  const float* xr = &x[n * Cin];
  for (int i = 0; i < Cin; i++) r = fmaf(xr[i], R[i * Cout + o], r);
  float v = s + r;
  h[tid] = v > 0.0f ? v : expm1f(v);
}

// ---------------- pool v4: h tile in LDS, n unrolled by 8; partial[c][j][o] ----------------
template <int COUT>
__global__ __launch_bounds__(256) void pool4_kernel(
    const float* __restrict__ P, const float* __restrict__ h,
    float* __restrict__ partial, int Nsrc, int Nnext, int chunk, int items) {
  extern __shared__ float hs[];
  int c = blockIdx.y;
  int n0 = c * chunk;
  int n1 = min(Nsrc, n0 + chunk);
  int len = n1 - n0;
  for (int t = threadIdx.x; t < len * (COUT / 4); t += 256)
    ((float4*)hs)[t] = ((const float4*)&h[(size_t)n0 * COUT])[t];
  __syncthreads();
  int item = blockIdx.x * 256 + threadIdx.x;
  if (item >= items) return;
  int nj4 = Nnext >> 2;
  int j0 = (item % nj4) << 2;
  int o0 = (item / nj4) << 3;
  float ac[4][8];
#pragma unroll
  for (int a = 0; a < 4; a++)
#pragma unroll
    for (int b = 0; b < 8; b++) ac[a][b] = 0.0f;
  const float* Pb = P + j0;
  int n = 0;
  for (; n + 8 <= len; n += 8) {
    float4 p[8];
#pragma unroll
    for (int u = 0; u < 8; u++)
      p[u] = *(const float4*)&Pb[(size_t)(n0 + n + u) * Nnext];
#pragma unroll
    for (int u = 0; u < 8; u++) {
      const float* hr = &hs[(n + u) * COUT + o0];
      float4 hA = *(const float4*)hr;
      float4 hB = *(const float4*)(hr + 4);
      float pj[4] = {p[u].x, p[u].y, p[u].z, p[u].w};
      float ho[8] = {hA.x, hA.y, hA.z, hA.w, hB.x, hB.y, hB.z, hB.w};
#pragma unroll
      for (int a = 0; a < 4; a++)
#pragma unroll
        for (int b = 0; b < 8; b++) ac[a][b] = fmaf(pj[a], ho[b], ac[a][b]);
    }
  }
  for (; n < len; n++) {
    float4 p = *(const float4*)&Pb[(size_t)(n0 + n) * Nnext];
    const float* hr = &hs[n * COUT + o0];
    float4 hA = *(const float4*)hr;
    float4 hB = *(const float4*)(hr + 4);
    float pj[4] = {p.x, p.y, p.z, p.w};
    float ho[8] = {hA.x, hA.y, hA.z, hA.w, hB.x, hB.y, hB.z, hB.w};
#pragma unroll
    for (int a = 0; a < 4; a++)
#pragma unroll
      for (int b = 0; b < 8; b++) ac[a][b] = fmaf(pj[a], ho[b], ac[a][b]);
  }
  float* pp = partial + ((size_t)c * Nnext + j0) * COUT + o0;
#pragma unroll
  for (int a = 0; a < 4; a++) {
    *(float4*)(pp + (size_t)a * COUT) =
        make_float4(ac[a][0], ac[a][1], ac[a][2], ac[a][3]);
    *(float4*)(pp + (size_t)a * COUT + 4) =
        make_float4(ac[a][4], ac[a][5], ac[a][6], ac[a][7]);
  }
}

// ---------------- pool reduce v2: one float per thread, coalesced, no atomics ----------------
__global__ __launch_bounds__(256) void preduce_kernel(
    const float* __restrict__ partial, float* __restrict__ xnext,
    int NnCout, int chunks) {
  int i = blockIdx.x * 256 + threadIdx.x;
  if (i >= NnCout) return;
  float s = 0.0f;
  for (int c = 0; c < chunks; c++) s += partial[(size_t)c * NnCout + i];
  xnext[i] = s;
}

// ---------------- final max over 16 nodes -> out[128] ----------------
__global__ __launch_bounds__(128) void max_kernel(const float* __restrict__ x6,
                                                  float* __restrict__ out) {
  int o = threadIdx.x;
  float m = -3.0e38f;
  for (int n = 0; n < 16; n++) m = fmaxf(m, x6[n * 128 + o]);
  out[o] = m;
}

extern "C" void kernel_launch(void* const* d_in, const int* in_sizes, int n_in,
                              void* d_out, int out_size, void* d_ws, size_t ws_size,
                              hipStream_t stream) {
  static const int NSh[7] = {20000, 5000, 1280, 320, 80, 32, 16};
  static const int ESh[6] = {320000, 80000, 20480, 5120, 1280, 512};
  static const int NFh[7] = {2, 16, 32, 64, 128, 128, 128};
  static const int cinSh[6]  = {1, 4, 5, 6, 7, 7};
  static const int coutSh[6] = {4, 5, 6, 7, 7, 7};
  static const int KSt[6] = {256, 2016, 4000, 8000, 16000, 16000};  // K padded to %32
  static const int kchunksTab[6] = {4, 8, 16, 32, 64, 128};
  static const int ktilesTab[6]  = {2, 8, 8, 8, 8, 4};   // kchunks*ktiles*32 >= KS
  static const int poolChunksTab[6] = {120, 64, 16, 8, 4, 2};

  const float* x0 = (const float*)d_in[0];
  const int* ei[6];
  const float* ea[6];
  for (int l = 0; l < 6; l++) {
    ei[l] = (const int*)d_in[1 + 2 * l];
    ea[l] = (const float*)d_in[2 + 2 * l];
  }
  const float* Pm[6];
  for (int l = 0; l < 6; l++) Pm[l] = (const float*)d_in[13 + l];
  const float* Wt[6];
  const float* Rt[6];
  const float* bt[6];
  for (int l = 0; l < 6; l++) {
    Wt[l] = (const float*)d_in[19 + 3 * l];
    Rt[l] = (const float*)d_in[20 + 3 * l];
    bt[l] = (const float*)d_in[21 + 3 * l];
  }

  // workspace layout (floats); ws_size ~1.6GB per round-3 poison-fill evidence, we use ~87MB
  float* ws = (float*)d_ws;
  float* A     = ws;                  // max N*KS = 5000*2016 = 10.08M
  float* degL  = ws + 10100000;       // max 20000
  float* gpart = ws + 10150000;       // max kchunks*N*Cout = 1.31M
  float* hbuf  = ws + 11500000;       // max 320000
  float* ppart = ws + 11900000;       // max pc*Nn*Cout = 9.6M
  float* xA    = ws + 21600000;       // 80000
  float* xB    = ws + 21700000;       // 80000

  const float* cur = x0;
  for (int l = 0; l < 6; l++) {
    int N = NSh[l], Nn = NSh[l + 1], Cin = NFh[l], Cout = NFh[l + 1], E = ESh[l];
    int Kdim = NKER * Cin, KS = KSt[l];
    float* xnext = (l & 1) ? xB : xA;

    hipMemsetAsync(A, 0, (size_t)N * KS * sizeof(float), stream);
    hipMemsetAsync(degL, 0, (size_t)N * sizeof(float), stream);

    int sthreads = E << cinSh[l];
    scatter_kernel<<<(sthreads + 255) / 256, 256, 0, stream>>>(
        ei[l], ea[l], cur, A, degL, E, cinSh[l], KS);

    int kchunks = kchunksTab[l], ktiles = ktilesTab[l];
    switch (l) {
      case 0: {
        dim3 g((N + 127) / 128, kchunks);
        gemm3_kernel<128, 16, 128><<<g, 128, 0, stream>>>(A, Wt[l], gpart, N, Kdim, KS, ktiles);
        break;
      }
      case 1: {
        dim3 g((N + 127) / 128, kchunks);
        gemm3_kernel<128, 32, 256><<<g, 256, 0, stream>>>(A, Wt[l], gpart, N, Kdim, KS, ktiles);
        break;
      }
      case 2: {
        dim3 g((N + 63) / 64, kchunks);
        gemm3_kernel<64, 64, 256><<<g, 256, 0, stream>>>(A, Wt[l], gpart, N, Kdim, KS, ktiles);
        break;
      }
      default: {
        dim3 g((N + 31) / 32, kchunks);
        gemm3_kernel<32, 128, 256><<<g, 256, 0, stream>>>(A, Wt[l], gpart, N, Kdim, KS, ktiles);
        break;
      }
    }

    int ethreads = N << coutSh[l];
    epilogue_kernel<<<(ethreads + 255) / 256, 256, 0, stream>>>(
        gpart, degL, cur, Rt[l], bt[l], hbuf, N, Cin, coutSh[l], kchunks);

    int pc = poolChunksTab[l];
    int chunk = (N + pc - 1) / pc;
    int items = (Nn >> 2) * (Cout >> 3);
    size_t ldsB = (size_t)chunk * Cout * sizeof(float);
    dim3 pgrid((items + 255) / 256, pc);
    switch (Cout) {
      case 16:
        pool4_kernel<16><<<pgrid, 256, ldsB, stream>>>(Pm[l], hbuf, ppart, N, Nn, chunk, items);
        break;
      case 32:
        pool4_kernel<32><<<pgrid, 256, ldsB, stream>>>(Pm[l], hbuf, ppart, N, Nn, chunk, items);
        break;
      case 64:
        pool4_kernel<64><<<pgrid, 256, ldsB, stream>>>(Pm[l], hbuf, ppart, N, Nn, chunk, items);
        break;
      default:
        pool4_kernel<128><<<pgrid, 256, ldsB, stream>>>(Pm[l], hbuf, ppart, N, Nn, chunk, items);
        break;
    }
    int NnCout = Nn << coutSh[l];
    preduce_kernel<<<(NnCout + 255) / 256, 256, 0, stream>>>(ppart, xnext, NnCout, pc);

    cur = xnext;
  }

  max_kernel<<<1, 128, 0, stream>>>(cur, (float*)d_out);
}

// Round 5
// 874.545 us; speedup vs baseline: 1.9706x; 1.0058x over previous
//
#include <hip/hip_runtime.h>
#include <math.h>

#define NKER 125

// ---------------- scatter: A[dst*KS + kidx*Cin + i] += wprod * x[src,ci]; deg[dst] += 1 ----------------
__global__ __launch_bounds__(256) void scatter_kernel(
    const int* __restrict__ ei, const float* __restrict__ ea,
    const float* __restrict__ x, float* __restrict__ A,
    float* __restrict__ deg, int E, int cinShift, int KS) {
  int tid = blockIdx.x * 256 + threadIdx.x;
  int Cin = 1 << cinShift;
  if (tid >= (E << cinShift)) return;
  int e = tid >> cinShift;
  int i = tid & (Cin - 1);
  int src = ei[e];
  int dst = ei[E + e];
  float xv = x[((size_t)src << cinShift) + i];
  float w[3][2];
  int k0[3];
#pragma unroll
  for (int d = 0; d < 3; d++) {
    float p = ea[e * 3 + d] * 4.0f;
    float kf = fminf(fmaxf(floorf(p), 0.0f), 3.0f);
    float f = p - kf;
    k0[d] = (int)kf;
    w[d][0] = 1.0f - f;
    w[d][1] = f;
  }
  float* Arow = A + (size_t)dst * KS + i;
#pragma unroll
  for (int c = 0; c < 8; c++) {
    int b0 = c & 1, b1 = (c >> 1) & 1, b2 = (c >> 2) & 1;
    float wp = w[0][b0] * w[1][b1] * w[2][b2];
    int kidx = (k0[0] + b0) + 5 * (k0[1] + b1) + 25 * (k0[2] + b2);
    atomicAdd(&Arow[kidx << cinShift], wp * xv);
  }
  if (i == 0) atomicAdd(&deg[dst], 1.0f);
}

// ---------------- GEMM v3: register-tiled 4x4, float4 staging, partials out (no atomics) ----------------
template <int BM, int COUT, int NT>
__global__ __launch_bounds__(NT) void gemm3_kernel(
    const float* __restrict__ A, const float* __restrict__ W,
    float* __restrict__ gpart, int M, int Kdim, int KS, int ktiles) {
  const int BK = 32;
  __shared__ float At[BK][BM + 4];
  __shared__ float Wl[BK][COUT];
  const int TC = COUT / 4;
  int tid = threadIdx.x;
  int tc = tid % TC;
  int tr = tid / TC;
  int m0 = blockIdx.x * BM;
  int kbeg = blockIdx.y * ktiles * BK;
  int kend = min(KS, kbeg + ktiles * BK);
  float ar[4][4];
#pragma unroll
  for (int i = 0; i < 4; i++)
#pragma unroll
    for (int j = 0; j < 4; j++) ar[i][j] = 0.0f;

  for (int k0 = kbeg; k0 < kend; k0 += BK) {
    for (int t = tid; t < BM * (BK / 4); t += NT) {
      int c4 = t % (BK / 4), r = t / (BK / 4);
      int m = m0 + r;
      float4 v = make_float4(0.0f, 0.0f, 0.0f, 0.0f);
      if (m < M) v = *(const float4*)&A[(size_t)m * KS + k0 + c4 * 4];
      At[c4 * 4 + 0][r] = v.x; At[c4 * 4 + 1][r] = v.y;
      At[c4 * 4 + 2][r] = v.z; At[c4 * 4 + 3][r] = v.w;
    }
    int kleft = Kdim - k0;
    if (kleft >= BK) {
      for (int t = tid; t < BK * COUT / 4; t += NT)
        ((float4*)&Wl[0][0])[t] = ((const float4*)&W[(size_t)k0 * COUT])[t];
    } else {
      for (int t = tid; t < BK * COUT; t += NT) {
        int kk = t / COUT, o = t % COUT;
        Wl[kk][o] = (kk < kleft) ? W[(size_t)(k0 + kk) * COUT + o] : 0.0f;
      }
    }
    __syncthreads();
#pragma unroll
    for (int kk = 0; kk < BK; kk++) {
      float4 a = *(const float4*)&At[kk][tr * 4];
      float4 w = *(const float4*)&Wl[kk][tc * 4];
      float av[4] = {a.x, a.y, a.z, a.w};
      float wv[4] = {w.x, w.y, w.z, w.w};
#pragma unroll
      for (int i = 0; i < 4; i++)
#pragma unroll
        for (int j = 0; j < 4; j++)
          ar[i][j] = fmaf(av[i], wv[j], ar[i][j]);
    }
    __syncthreads();
  }
  float* gp = gpart + ((size_t)blockIdx.y * M) * COUT + tc * 4;
#pragma unroll
  for (int i = 0; i < 4; i++) {
    int m = m0 + tr * 4 + i;
    if (m < M)
      *(float4*)(gp + (size_t)m * COUT) =
          make_float4(ar[i][0], ar[i][1], ar[i][2], ar[i][3]);
  }
}

// ---------------- epilogue: h = elu(sum_c gpart[c]/max(deg,1) + x@R + b) ----------------
__global__ __launch_bounds__(256) void epilogue_kernel(
    const float* __restrict__ gpart, const float* __restrict__ deg,
    const float* __restrict__ x, const float* __restrict__ R,
    const float* __restrict__ b, float* __restrict__ h,
    int N, int Cin, int coutShift, int kchunks) {
  int tid = blockIdx.x * 256 + threadIdx.x;
  int Cout = 1 << coutShift;
  if (tid >= (N << coutShift)) return;
  int n = tid >> coutShift;
  int o = tid & (Cout - 1);
  size_t stride = (size_t)N << coutShift;
  float s = 0.0f;
  for (int c = 0; c < kchunks; c++) s += gpart[(size_t)c * stride + tid];
  s /= fmaxf(deg[n], 1.0f);
  float r = b[o];
  const float* xr = &x[n * Cin];
  for (int i = 0; i < Cin; i++) r = fmaf(xr[i], R[i * Cout + o], r);
  float v = s + r;
  h[tid] = v > 0.0f ? v : expm1f(v);
}

// ---------------- pool v5: h tile in LDS, OPT outputs per thread, n unrolled by 8 ----------------
template <int COUT, int OPT>
__global__ __launch_bounds__(256) void pool5_kernel(
    const float* __restrict__ P, const float* __restrict__ h,
    float* __restrict__ partial, int Nsrc, int Nnext, int chunk, int items) {
  extern __shared__ float hs[];
  int c = blockIdx.y;
  int n0 = c * chunk;
  int n1 = min(Nsrc, n0 + chunk);
  int len = n1 - n0;
  for (int t = threadIdx.x; t < len * (COUT / 4); t += 256)
    ((float4*)hs)[t] = ((const float4*)&h[(size_t)n0 * COUT])[t];
  __syncthreads();
  int item = blockIdx.x * 256 + threadIdx.x;
  if (item >= items) return;
  int nj4 = Nnext >> 2;
  int j0 = (item % nj4) << 2;
  int o0 = (item / nj4) * OPT;
  float ac[4][OPT];
#pragma unroll
  for (int a = 0; a < 4; a++)
#pragma unroll
    for (int b = 0; b < OPT; b++) ac[a][b] = 0.0f;
  const float* Pb = P + j0;
  int n = 0;
  for (; n + 8 <= len; n += 8) {
    float4 p[8];
#pragma unroll
    for (int u = 0; u < 8; u++)
      p[u] = *(const float4*)&Pb[(size_t)(n0 + n + u) * Nnext];
#pragma unroll
    for (int u = 0; u < 8; u++) {
      const float4* hr = (const float4*)&hs[(n + u) * COUT + o0];
      float pj[4] = {p[u].x, p[u].y, p[u].z, p[u].w};
#pragma unroll
      for (int q = 0; q < OPT / 4; q++) {
        float4 hv = hr[q];
        float ho[4] = {hv.x, hv.y, hv.z, hv.w};
#pragma unroll
        for (int a = 0; a < 4; a++)
#pragma unroll
          for (int t = 0; t < 4; t++)
            ac[a][q * 4 + t] = fmaf(pj[a], ho[t], ac[a][q * 4 + t]);
      }
    }
  }
  for (; n < len; n++) {
    float4 p = *(const float4*)&Pb[(size_t)(n0 + n) * Nnext];
    const float4* hr = (const float4*)&hs[n * COUT + o0];
    float pj[4] = {p.x, p.y, p.z, p.w};
#pragma unroll
    for (int q = 0; q < OPT / 4; q++) {
      float4 hv = hr[q];
      float ho[4] = {hv.x, hv.y, hv.z, hv.w};
#pragma unroll
      for (int a = 0; a < 4; a++)
#pragma unroll
        for (int t = 0; t < 4; t++)
          ac[a][q * 4 + t] = fmaf(pj[a], ho[t], ac[a][q * 4 + t]);
    }
  }
  float* pp = partial + ((size_t)c * Nnext + j0) * COUT + o0;
#pragma unroll
  for (int a = 0; a < 4; a++)
#pragma unroll
    for (int q = 0; q < OPT / 4; q++)
      *(float4*)(pp + (size_t)a * COUT + q * 4) =
          make_float4(ac[a][q * 4 + 0], ac[a][q * 4 + 1],
                      ac[a][q * 4 + 2], ac[a][q * 4 + 3]);
}

// ---------------- pool reduce: one float per thread, coalesced, no atomics ----------------
__global__ __launch_bounds__(256) void preduce_kernel(
    const float* __restrict__ partial, float* __restrict__ xnext,
    int NnCout, int chunks) {
  int i = blockIdx.x * 256 + threadIdx.x;
  if (i >= NnCout) return;
  float s = 0.0f;
  for (int c = 0; c < chunks; c++) s += partial[(size_t)c * NnCout + i];
  xnext[i] = s;
}

// ---------------- final max over 16 nodes -> out[128] ----------------
__global__ __launch_bounds__(128) void max_kernel(const float* __restrict__ x6,
                                                  float* __restrict__ out) {
  int o = threadIdx.x;
  float m = -3.0e38f;
  for (int n = 0; n < 16; n++) m = fmaxf(m, x6[n * 128 + o]);
  out[o] = m;
}

extern "C" void kernel_launch(void* const* d_in, const int* in_sizes, int n_in,
                              void* d_out, int out_size, void* d_ws, size_t ws_size,
                              hipStream_t stream) {
  static const int NSh[7] = {20000, 5000, 1280, 320, 80, 32, 16};
  static const int ESh[6] = {320000, 80000, 20480, 5120, 1280, 512};
  static const int NFh[7] = {2, 16, 32, 64, 128, 128, 128};
  static const int cinSh[6]  = {1, 4, 5, 6, 7, 7};
  static const int coutSh[6] = {4, 5, 6, 7, 7, 7};
  static const int KSt[6] = {256, 2016, 4000, 8000, 16000, 16000};  // K padded to %32
  static const int kchunksTab[6] = {4, 8, 16, 32, 64, 128};
  static const int ktilesTab[6]  = {2, 8, 8, 8, 8, 4};   // kchunks*ktiles*32 >= KS
  static const int poolChunksTab[6] = {120, 64, 16, 8, 4, 2};

  const float* x0 = (const float*)d_in[0];
  const int* ei[6];
  const float* ea[6];
  for (int l = 0; l < 6; l++) {
    ei[l] = (const int*)d_in[1 + 2 * l];
    ea[l] = (const float*)d_in[2 + 2 * l];
  }
  const float* Pm[6];
  for (int l = 0; l < 6; l++) Pm[l] = (const float*)d_in[13 + l];
  const float* Wt[6];
  const float* Rt[6];
  const float* bt[6];
  for (int l = 0; l < 6; l++) {
    Wt[l] = (const float*)d_in[19 + 3 * l];
    Rt[l] = (const float*)d_in[20 + 3 * l];
    bt[l] = (const float*)d_in[21 + 3 * l];
  }

  // workspace layout (floats); ws ~1.6GB, we use ~87MB
  float* ws = (float*)d_ws;
  float* A     = ws;                  // max N*KS + N (deg) = 10.085M floats (layer 1)
  float* gpart = ws + 10150000;       // max kchunks*N*Cout = 1.31M
  float* hbuf  = ws + 11500000;       // max 320000
  float* ppart = ws + 11900000;       // max pc*Nn*Cout = 9.6M
  float* xA    = ws + 21600000;       // 80000
  float* xB    = ws + 21700000;       // 80000

  const float* cur = x0;
  for (int l = 0; l < 6; l++) {
    int N = NSh[l], Nn = NSh[l + 1], Cin = NFh[l], Cout = NFh[l + 1], E = ESh[l];
    int Kdim = NKER * Cin, KS = KSt[l];
    float* xnext = (l & 1) ? xB : xA;
    float* degL = A + (size_t)N * KS;   // deg contiguous with A -> one memset

    hipMemsetAsync(A, 0, ((size_t)N * KS + N) * sizeof(float), stream);

    int sthreads = E << cinSh[l];
    scatter_kernel<<<(sthreads + 255) / 256, 256, 0, stream>>>(
        ei[l], ea[l], cur, A, degL, E, cinSh[l], KS);

    int kchunks = kchunksTab[l], ktiles = ktilesTab[l];
    switch (l) {
      case 0: {
        dim3 g((N + 127) / 128, kchunks);
        gemm3_kernel<128, 16, 128><<<g, 128, 0, stream>>>(A, Wt[l], gpart, N, Kdim, KS, ktiles);
        break;
      }
      case 1: {
        dim3 g((N + 127) / 128, kchunks);
        gemm3_kernel<128, 32, 256><<<g, 256, 0, stream>>>(A, Wt[l], gpart, N, Kdim, KS, ktiles);
        break;
      }
      case 2: {
        dim3 g((N + 63) / 64, kchunks);
        gemm3_kernel<64, 64, 256><<<g, 256, 0, stream>>>(A, Wt[l], gpart, N, Kdim, KS, ktiles);
        break;
      }
      default: {
        dim3 g((N + 31) / 32, kchunks);
        gemm3_kernel<32, 128, 256><<<g, 256, 0, stream>>>(A, Wt[l], gpart, N, Kdim, KS, ktiles);
        break;
      }
    }

    int ethreads = N << coutSh[l];
    epilogue_kernel<<<(ethreads + 255) / 256, 256, 0, stream>>>(
        gpart, degL, cur, Rt[l], bt[l], hbuf, N, Cin, coutSh[l], kchunks);

    int pc = poolChunksTab[l];
    int chunk = (N + pc - 1) / pc;
    size_t ldsB = (size_t)chunk * Cout * sizeof(float);
    // OPT: 16 outputs/thread for Cout<=32 (P read 1-2x), 8 for bigger Cout (P tiny there)
    int items, gx;
    switch (Cout) {
      case 16:
        items = (Nn >> 2) * (16 / 16);
        gx = (items + 255) / 256;
        pool5_kernel<16, 16><<<dim3(gx, pc), 256, ldsB, stream>>>(Pm[l], hbuf, ppart, N, Nn, chunk, items);
        break;
      case 32:
        items = (Nn >> 2) * (32 / 16);
        gx = (items + 255) / 256;
        pool5_kernel<32, 16><<<dim3(gx, pc), 256, ldsB, stream>>>(Pm[l], hbuf, ppart, N, Nn, chunk, items);
        break;
      case 64:
        items = (Nn >> 2) * (64 / 8);
        gx = (items + 255) / 256;
        pool5_kernel<64, 8><<<dim3(gx, pc), 256, ldsB, stream>>>(Pm[l], hbuf, ppart, N, Nn, chunk, items);
        break;
      default:
        items = (Nn >> 2) * (128 / 8);
        gx = (items + 255) / 256;
        pool5_kernel<128, 8><<<dim3(gx, pc), 256, ldsB, stream>>>(Pm[l], hbuf, ppart, N, Nn, chunk, items);
        break;
    }
    int NnCout = Nn << coutSh[l];
    preduce_kernel<<<(NnCout + 255) / 256, 256, 0, stream>>>(ppart, xnext, NnCout, pc);

    cur = xnext;
  }

  max_kernel<<<1, 128, 0, stream>>>(cur, (float*)d_out);
}